// Round 9
// baseline (106.266 us; speedup 1.0000x reference)
//
#include <hip/hip_runtime.h>

#define NCLS 19
#define HWPIX (512 * 512)
#define NB 8
#define PBI 128                // blocks per image
#define PIXB 2048              // pixels per block (128*2048 == HWPIX)
#define NACC 57                // rows: S(0..18) | TP(19..37) | N(38..56)
#define NCOPY 64
#define ALPHA_C 0.7f
#define BETA_C 0.3f
#define EPS_C 1e-7f
#define L2E 1.44269504088896f

// R9: channel-decorrelation. A block's 19 class streams differ only in
// bits >=20 (1 MiB stride) -> identical low bits -> same HBM/L2 channels ->
// per-block channel-queue serialization, invariant to occupancy/VGPR/DMA
// (the R0-R8 result). Fix: class-SEQUENTIAL two-pass over a block-owned
// contiguous 2048-pixel slab. At any instant a wave streams ONE contiguous
// run of ONE class (channel-spread); blocks stagger their class order
// (rot = blockIdx % 19). Threads own disjoint pixels -> pass A/B need no
// barriers and no atomics on the sum array. Pass B re-read is L3-resident.
// Exp is computed twice per element (VALU ~9us/SIMD, under the memory floor).
__global__ __launch_bounds__(256, 4) void ftl_fused(
    const float* __restrict__ x,    // [B, C, H, W]
    const int* __restrict__ tgt,    // [B, H, W]
    float* __restrict__ part,       // [NB*PBI][NACC]
    int* __restrict__ counter,      // zeroed by hipMemsetAsync pre-launch
    float* __restrict__ out) {
  const int b = blockIdx.x / PBI;
  const int blk = blockIdx.x % PBI;
  const int tid = threadIdx.x;

  __shared__ float bins[NACC][NCOPY];  // 64-copy histogram rows
  __shared__ float invs[PIXB];         // sum-of-exp -> reciprocal, in place
  __shared__ unsigned tgt8[PIXB / 4];  // 4 packed u8 targets per word
  __shared__ float fin[NB * NACC];
  __shared__ float wsum[4];
  __shared__ int lastFlag;

  for (int i = tid; i < NACC * NCOPY; i += 256) (&bins[0][0])[i] = 0.f;
  __syncthreads();  // bins zero before any atomic

  const float* xb = x + (size_t)b * NCLS * HWPIX + blk * PIXB;
  const int* tb = tgt + (size_t)b * HWPIX + blk * PIXB;
  const int cp = tid & (NCOPY - 1);
  const int rot = blockIdx.x % NCLS;

  // ---- stage targets (own pixels) + N histogram ----
#pragma unroll
  for (int k = 0; k < 2; ++k) {
    const int4 t4 = *reinterpret_cast<const int4*>(tb + k * 1024 + tid * 4);
    tgt8[k * 256 + tid] = (unsigned)t4.x | ((unsigned)t4.y << 8) |
                          ((unsigned)t4.z << 16) | ((unsigned)t4.w << 24);
    atomicAdd(&bins[38 + t4.x][cp], 1.f);
    atomicAdd(&bins[38 + t4.y][cp], 1.f);
    atomicAdd(&bins[38 + t4.z][cp], 1.f);
    atomicAdd(&bins[38 + t4.w][cp], 1.f);
  }

  // ---- pass A: sum of exp per pixel, class-sequential, depth-1 prefetch ----
  {
    const float* p0 = xb + (size_t)rot * HWPIX;
    float4 v0 = *reinterpret_cast<const float4*>(p0 + tid * 4);
    float4 v1 = *reinterpret_cast<const float4*>(p0 + 1024 + tid * 4);
    for (int cc = 0; cc < NCLS; ++cc) {
      float4 n0, n1;
      if (cc + 1 < NCLS) {
        int cn = rot + cc + 1;
        if (cn >= NCLS) cn -= NCLS;
        const float* pn = xb + (size_t)cn * HWPIX;
        n0 = *reinterpret_cast<const float4*>(pn + tid * 4);
        n1 = *reinterpret_cast<const float4*>(pn + 1024 + tid * 4);
      }
      float4 e0, e1;
      e0.x = __builtin_amdgcn_exp2f(v0.x * L2E);
      e0.y = __builtin_amdgcn_exp2f(v0.y * L2E);
      e0.z = __builtin_amdgcn_exp2f(v0.z * L2E);
      e0.w = __builtin_amdgcn_exp2f(v0.w * L2E);
      e1.x = __builtin_amdgcn_exp2f(v1.x * L2E);
      e1.y = __builtin_amdgcn_exp2f(v1.y * L2E);
      e1.z = __builtin_amdgcn_exp2f(v1.z * L2E);
      e1.w = __builtin_amdgcn_exp2f(v1.w * L2E);
      float4* s0 = reinterpret_cast<float4*>(&invs[tid * 4]);
      float4* s1 = reinterpret_cast<float4*>(&invs[1024 + tid * 4]);
      if (cc == 0) {          // first class initializes (no zero-fill pass)
        *s0 = e0;
        *s1 = e1;
      } else {                // own pixels only: plain LDS RMW, no atomics
        float4 a0 = *s0, a1 = *s1;
        a0.x += e0.x; a0.y += e0.y; a0.z += e0.z; a0.w += e0.w;
        a1.x += e1.x; a1.y += e1.y; a1.z += e1.z; a1.w += e1.w;
        *s0 = a0;
        *s1 = a1;
      }
      if (cc + 1 < NCLS) { v0 = n0; v1 = n1; }
    }
  }

  // ---- sum -> reciprocal in place (own pixels) ----
#pragma unroll
  for (int k = 0; k < 2; ++k) {
    float4* sp = reinterpret_cast<float4*>(&invs[k * 1024 + tid * 4]);
    float4 s4 = *sp;
    s4.x = __builtin_amdgcn_rcpf(s4.x);
    s4.y = __builtin_amdgcn_rcpf(s4.y);
    s4.z = __builtin_amdgcn_rcpf(s4.z);
    s4.w = __builtin_amdgcn_rcpf(s4.w);
    *sp = s4;
  }

  // ---- pass B: re-stream classes (L3-hot), accumulate S and TP ----
  {
    const float4 i0 = *reinterpret_cast<const float4*>(&invs[tid * 4]);
    const float4 i1 = *reinterpret_cast<const float4*>(&invs[1024 + tid * 4]);
    const unsigned tw0 = tgt8[tid];
    const unsigned tw1 = tgt8[256 + tid];
    const float* p0 = xb + (size_t)rot * HWPIX;
    float4 v0 = *reinterpret_cast<const float4*>(p0 + tid * 4);
    float4 v1 = *reinterpret_cast<const float4*>(p0 + 1024 + tid * 4);
    for (int cc = 0; cc < NCLS; ++cc) {
      int c = rot + cc;
      if (c >= NCLS) c -= NCLS;
      float4 n0, n1;
      if (cc + 1 < NCLS) {
        int cn = rot + cc + 1;
        if (cn >= NCLS) cn -= NCLS;
        const float* pn = xb + (size_t)cn * HWPIX;
        n0 = *reinterpret_cast<const float4*>(pn + tid * 4);
        n1 = *reinterpret_cast<const float4*>(pn + 1024 + tid * 4);
      }
      float4 q0, q1;
      q0.x = __builtin_amdgcn_exp2f(v0.x * L2E) * i0.x;
      q0.y = __builtin_amdgcn_exp2f(v0.y * L2E) * i0.y;
      q0.z = __builtin_amdgcn_exp2f(v0.z * L2E) * i0.z;
      q0.w = __builtin_amdgcn_exp2f(v0.w * L2E) * i0.w;
      q1.x = __builtin_amdgcn_exp2f(v1.x * L2E) * i1.x;
      q1.y = __builtin_amdgcn_exp2f(v1.y * L2E) * i1.y;
      q1.z = __builtin_amdgcn_exp2f(v1.z * L2E) * i1.z;
      q1.w = __builtin_amdgcn_exp2f(v1.w * L2E) * i1.w;
      const float sacc = (q0.x + q0.y) + (q0.z + q0.w) +
                         (q1.x + q1.y) + (q1.z + q1.w);
      float tp = 0.f;
      tp += ((int)((tw0)       & 255u) == c) ? q0.x : 0.f;
      tp += ((int)((tw0 >> 8)  & 255u) == c) ? q0.y : 0.f;
      tp += ((int)((tw0 >> 16) & 255u) == c) ? q0.z : 0.f;
      tp += ((int)((tw0 >> 24) & 255u) == c) ? q0.w : 0.f;
      tp += ((int)((tw1)       & 255u) == c) ? q1.x : 0.f;
      tp += ((int)((tw1 >> 8)  & 255u) == c) ? q1.y : 0.f;
      tp += ((int)((tw1 >> 16) & 255u) == c) ? q1.z : 0.f;
      tp += ((int)((tw1 >> 24) & 255u) == c) ? q1.w : 0.f;
      atomicAdd(&bins[c][cp], sacc);        // 64-copy rows: zero contention
      atomicAdd(&bins[19 + c][cp], tp);
      if (cc + 1 < NCLS) { v0 = n0; v1 = n1; }
    }
  }
  __syncthreads();  // bins complete

  // ---- block epilogue: 4 lanes per row sum the 64 copies ----
  float* myPart = part + (size_t)blockIdx.x * NACC;
  if (tid < NACC * 4) {
    const int a = tid >> 2, qd = tid & 3;
    float v = 0.f;
#pragma unroll
    for (int i = 0; i < NCOPY / 4; ++i) v += bins[a][qd * (NCOPY / 4) + i];
    v += __shfl_down(v, 1);
    v += __shfl_down(v, 2);
    if (qd == 0) myPart[a] = v;
  }

  // ---- device-scope ticket; last block finalizes ----
  __syncthreads();  // partial stores drained before fence/ticket
  if (tid == 0) {
    __threadfence();  // release this block's slice
    lastFlag = (atomicAdd(counter, 1) == NB * PBI - 1);
  }
  __syncthreads();
  if (!lastFlag) return;
  __threadfence();    // acquire all slices

  for (int pr = tid; pr < NB * NACC; pr += 256) {
    const int bb = pr / NACC, aa = pr % NACC;
    const float* q = part + (size_t)bb * PBI * NACC + aa;
    float v = 0.f;
#pragma unroll 8
    for (int p = 0; p < PBI; ++p) v += q[(size_t)p * NACC];
    fin[pr] = v;
  }
  __syncthreads();

  float v = 0.f;
  if (tid < NB * NCLS) {
    const int bb = tid / NCLS, c = tid % NCLS;
    const float Sv = fin[bb * NACC + c];
    const float TPv = fin[bb * NACC + 19 + c];
    const float Ncv = fin[bb * NACC + 38 + c];
    const float FPv = Sv - TPv;
    const float FNv = Ncv - TPv;
    const float tv = (TPv + EPS_C) / (TPv + ALPHA_C * FNv + BETA_C * FPv + EPS_C);
    v = 1.0f - tv;  // GAMMA == 1.0
  }
  for (int off = 32; off; off >>= 1) v += __shfl_down(v, off);
  if ((tid & 63) == 0) wsum[tid >> 6] = v;
  __syncthreads();
  if (tid == 0) out[0] = (wsum[0] + wsum[1] + wsum[2] + wsum[3]) / (float)NB;
}

extern "C" void kernel_launch(void* const* d_in, const int* in_sizes, int n_in,
                              void* d_out, int out_size, void* d_ws, size_t ws_size,
                              hipStream_t stream) {
  const float* x = (const float*)d_in[0];
  const int* tgt = (const int*)d_in[1];
  float* out = (float*)d_out;
  float* part = (float*)d_ws;
  int* counter = (int*)(part + (size_t)NB * PBI * NACC);  // after partials

  hipMemsetAsync(counter, 0, sizeof(int), stream);  // graph-capturable
  ftl_fused<<<NB * PBI, 256, 0, stream>>>(x, tgt, part, counter, out);
}

// Round 10
// 71.184 us; speedup vs baseline: 1.4928x; 1.4928x over previous
//
#include <hip/hip_runtime.h>

#define NCLS 19
#define HWPIX (512 * 512)
#define NB 8
#define PB 64
#define ALPHA_C 0.7f
#define BETA_C 0.3f
#define EPS_C 1e-7f
#define L2E 1.44269504088896f

typedef float v2f __attribute__((ext_vector_type(2)));
typedef float v4f __attribute__((ext_vector_type(4)));

// R10: exact R5 (session champion, 49.4 us) with ONE change: the 19 class
// streams load via __builtin_nontemporal_load (global_load_dwordx4 nt).
// Theory: all R0-R9 read structures converge to ~1-1.8 TB/s HBM fetch
// (one miss-instruction serviced per ~500-900 cy per CU) while fillBuffer
// writes at 7 TB/s in the same sessions -> the per-CU read-miss path
// (L1 allocation/tracking for use-once streaming lines) is the invariant
// bottleneck, the one subsystem never yet varied. nt = no-allocate hint,
// the read-side analog of the (fast) write path. Gathers/targets stay
// plain loads (they want the cached lines).
__global__ __launch_bounds__(256, 3) void ftl_fused(
    const float* __restrict__ x,    // [B, C, H, W]
    const int* __restrict__ tgt,    // [B, H, W]
    float* __restrict__ part,       // [B*PB][3*NCLS]  (S | TP | N)
    int* __restrict__ counter,      // zeroed by hipMemsetAsync pre-launch
    float* __restrict__ out) {
  const int b = blockIdx.x / PB;
  const int blk = blockIdx.x % PB;
  const int tid = threadIdx.x;

  __shared__ float sTPb[NCLS][32];
  __shared__ int sNb[NCLS][32];
  __shared__ float sS[NCLS];
  for (int i = tid; i < NCLS * 32; i += 256) {
    (&sTPb[0][0])[i] = 0.f;
    (&sNb[0][0])[i] = 0;
  }
  if (tid < NCLS) sS[tid] = 0.f;
  __syncthreads();

  const int quadsPerBlock = (HWPIX / 4) / PB;  // 1024
  const int qbase = blk * quadsPerBlock;
  const float* xb = x + (size_t)b * NCLS * HWPIX;
  const int* tb = tgt + (size_t)b * HWPIX;
  const int cp = tid & 31;  // private-ish histogram copy (bank == copy)

  v2f S2[NCLS];
#pragma unroll
  for (int c = 0; c < NCLS; ++c) S2[c] = (v2f){0.f, 0.f};

  for (int q = tid; q < quadsPerBlock; q += 256) {
    const int pix = (qbase + q) * 4;
    const int4 t = *reinterpret_cast<const int4*>(tb + pix);

    v2f ea[NCLS], eb[NCLS];
    v2f sea = (v2f){0.f, 0.f}, seb = (v2f){0.f, 0.f};
#pragma unroll
    for (int c = 0; c < NCLS; ++c) {
      const v4f xv = __builtin_nontemporal_load(
          reinterpret_cast<const v4f*>(xb + (size_t)c * HWPIX + pix));
      const v2f a = (v2f){xv.x, xv.y} * L2E;   // v_pk_mul_f32
      const v2f bb = (v2f){xv.z, xv.w} * L2E;
      ea[c] = (v2f){__builtin_amdgcn_exp2f(a.x), __builtin_amdgcn_exp2f(a.y)};
      eb[c] = (v2f){__builtin_amdgcn_exp2f(bb.x), __builtin_amdgcn_exp2f(bb.y)};
      sea += ea[c];                            // v_pk_add_f32
      seb += eb[c];
    }
    const v2f inva = (v2f){__builtin_amdgcn_rcpf(sea.x), __builtin_amdgcn_rcpf(sea.y)};
    const v2f invb = (v2f){__builtin_amdgcn_rcpf(seb.x), __builtin_amdgcn_rcpf(seb.y)};
#pragma unroll
    for (int c = 0; c < NCLS; ++c) {
      S2[c] += ea[c] * inva;                   // v_pk_fma_f32
      S2[c] += eb[c] * invb;
    }

    // Target-class gather after the stream loads (plain loads: want caching).
    const v2f xta = (v2f){xb[(size_t)t.x * HWPIX + pix + 0],
                          xb[(size_t)t.y * HWPIX + pix + 1]} * L2E;
    const v2f xtb = (v2f){xb[(size_t)t.z * HWPIX + pix + 2],
                          xb[(size_t)t.w * HWPIX + pix + 3]} * L2E;
    const v2f pta = (v2f){__builtin_amdgcn_exp2f(xta.x),
                          __builtin_amdgcn_exp2f(xta.y)} * inva;
    const v2f ptb = (v2f){__builtin_amdgcn_exp2f(xtb.x),
                          __builtin_amdgcn_exp2f(xtb.y)} * invb;
    atomicAdd(&sTPb[t.x][cp], pta.x);
    atomicAdd(&sTPb[t.y][cp], pta.y);
    atomicAdd(&sTPb[t.z][cp], ptb.x);
    atomicAdd(&sTPb[t.w][cp], ptb.y);
    atomicAdd(&sNb[t.x][cp], 1);
    atomicAdd(&sNb[t.y][cp], 1);
    atomicAdd(&sNb[t.z][cp], 1);
    atomicAdd(&sNb[t.w][cp], 1);
  }

  // Reduce S: fold pair, wave butterfly, wave leaders merge in LDS.
#pragma unroll
  for (int c = 0; c < NCLS; ++c) {
    float Sc = S2[c].x + S2[c].y;
    for (int off = 32; off; off >>= 1) Sc += __shfl_down(Sc, off);
    if ((tid & 63) == 0) atomicAdd(&sS[c], Sc);
  }
  __syncthreads();
  if (tid < NCLS) {
    float tp = 0.f;
    int n = 0;
#pragma unroll
    for (int i = 0; i < 32; ++i) { tp += sTPb[tid][i]; n += sNb[tid][i]; }
    float* p = part + (size_t)blockIdx.x * (3 * NCLS);
    p[tid] = sS[tid];
    p[NCLS + tid] = tp;
    p[2 * NCLS + tid] = (float)n;
  }

  // ---- last-block final reduction ----
  __syncthreads();  // part-slice stores drained (waitcnt before barrier)
  __shared__ int lastFlag;
  if (tid == 0) {
    __threadfence();  // release: make this block's slice device-visible
    lastFlag = (atomicAdd(counter, 1) == (NB * PB - 1));
  }
  __syncthreads();
  if (!lastFlag) return;
  __threadfence();  // acquire: invalidate stale cached partials

  float v = 0.f;
  if (tid < NB * NCLS) {
    const int bb = tid / NCLS;
    const int c = tid % NCLS;
    float S = 0.f, TP = 0.f, Nc = 0.f;
#pragma unroll 16
    for (int p = 0; p < PB; ++p) {
      const float* q = part + (size_t)(bb * PB + p) * (3 * NCLS);
      S += q[c];
      TP += q[NCLS + c];
      Nc += q[2 * NCLS + c];
    }
    const float FPv = S - TP;
    const float FNv = Nc - TP;
    const float tv = (TP + EPS_C) / (TP + ALPHA_C * FNv + BETA_C * FPv + EPS_C);
    v = 1.0f - tv;  // GAMMA == 1.0
  }
  for (int off = 32; off; off >>= 1) v += __shfl_down(v, off);
  __shared__ float wsum[4];
  if ((tid & 63) == 0) wsum[tid >> 6] = v;
  __syncthreads();
  if (tid == 0) out[0] = (wsum[0] + wsum[1] + wsum[2] + wsum[3]) / (float)NB;
}

extern "C" void kernel_launch(void* const* d_in, const int* in_sizes, int n_in,
                              void* d_out, int out_size, void* d_ws, size_t ws_size,
                              hipStream_t stream) {
  const float* x = (const float*)d_in[0];
  const int* tgt = (const int*)d_in[1];
  float* out = (float*)d_out;
  float* part = (float*)d_ws;
  int* counter = (int*)(part + NB * PB * 3 * NCLS);  // right after partials

  hipMemsetAsync(counter, 0, sizeof(int), stream);  // graph-capturable
  ftl_fused<<<NB * PB, 256, 0, stream>>>(x, tgt, part, counter, out);
}

// Round 11
// 65.326 us; speedup vs baseline: 1.6267x; 1.0897x over previous
//
#include <hip/hip_runtime.h>

#define NCLS 19
#define HWPIX (512 * 512)
#define NB 8
#define PB 64
#define ALPHA_C 0.7f
#define BETA_C 0.3f
#define EPS_C 1e-7f
#define L2E 1.44269504088896f

typedef float v2f __attribute__((ext_vector_type(2)));

// R11: R5 (champion, 49.4us) + explicit depth-1 software pipeline of the
// 19-class float4 stream loads, enabled by __launch_bounds__(256,2)
// (256-VGPR budget; R5's (256,3) capped at 168 and forced the compiler to
// serialize load-burst -> compute). Theory: the invariant ~3.4 TB/s across
// R0-R10 is duty-cycle-limited latency hiding (avg ~5 KB/CU outstanding
// because nothing is in flight during the ~1000cy compute phase). With
// next-iteration prefetch held in registers, each wave sustains ~19 KB in
// flight through compute: 8 waves/CU -> ~150 KB/CU vs ~10 KB needed.
// Everything else (bins, gathers, ticket tail) identical to R5.
__global__ __launch_bounds__(256, 2) void ftl_fused(
    const float* __restrict__ x,    // [B, C, H, W]
    const int* __restrict__ tgt,    // [B, H, W]
    float* __restrict__ part,       // [B*PB][3*NCLS]  (S | TP | N)
    int* __restrict__ counter,      // zeroed by hipMemsetAsync pre-launch
    float* __restrict__ out) {
  const int b = blockIdx.x / PB;
  const int blk = blockIdx.x % PB;
  const int tid = threadIdx.x;

  __shared__ float sTPb[NCLS][32];
  __shared__ int sNb[NCLS][32];
  __shared__ float sS[NCLS];
  for (int i = tid; i < NCLS * 32; i += 256) {
    (&sTPb[0][0])[i] = 0.f;
    (&sNb[0][0])[i] = 0;
  }
  if (tid < NCLS) sS[tid] = 0.f;
  __syncthreads();

  const int quadsPerBlock = (HWPIX / 4) / PB;  // 1024 -> 4 iters/thread
  const int qbase = blk * quadsPerBlock;
  const float* xb = x + (size_t)b * NCLS * HWPIX;
  const int* tb = tgt + (size_t)b * HWPIX;
  const int cp = tid & 31;  // private-ish histogram copy (bank == copy)

  v2f S2[NCLS];
#pragma unroll
  for (int c = 0; c < NCLS; ++c) S2[c] = (v2f){0.f, 0.f};

  // Prologue: load iteration 0's 19 streams into registers.
  float4 cur[NCLS];
  {
    const int pix0 = (qbase + tid) * 4;
#pragma unroll
    for (int c = 0; c < NCLS; ++c)
      cur[c] = *reinterpret_cast<const float4*>(xb + (size_t)c * HWPIX + pix0);
  }

  for (int q = tid; q < quadsPerBlock; q += 256) {
    const int pix = (qbase + q) * 4;
    const int4 t = *reinterpret_cast<const int4*>(tb + pix);

    // ---- issue NEXT iteration's 19 stream loads (stay in flight during
    // this iteration's compute; consumed at the bottom copy) ----
    float4 nxt[NCLS];
    const int qn = q + 256;
    if (qn < quadsPerBlock) {
      const int pixn = (qbase + qn) * 4;
#pragma unroll
      for (int c = 0; c < NCLS; ++c)
        nxt[c] = *reinterpret_cast<const float4*>(xb + (size_t)c * HWPIX + pixn);
    }

    // ---- compute on cur ----
    v2f ea[NCLS], eb[NCLS];
    v2f sea = (v2f){0.f, 0.f}, seb = (v2f){0.f, 0.f};
#pragma unroll
    for (int c = 0; c < NCLS; ++c) {
      const v2f a = (v2f){cur[c].x, cur[c].y} * L2E;   // v_pk_mul_f32
      const v2f bb = (v2f){cur[c].z, cur[c].w} * L2E;
      ea[c] = (v2f){__builtin_amdgcn_exp2f(a.x), __builtin_amdgcn_exp2f(a.y)};
      eb[c] = (v2f){__builtin_amdgcn_exp2f(bb.x), __builtin_amdgcn_exp2f(bb.y)};
      sea += ea[c];                                    // v_pk_add_f32
      seb += eb[c];
    }
    const v2f inva = (v2f){__builtin_amdgcn_rcpf(sea.x), __builtin_amdgcn_rcpf(sea.y)};
    const v2f invb = (v2f){__builtin_amdgcn_rcpf(seb.x), __builtin_amdgcn_rcpf(seb.y)};
#pragma unroll
    for (int c = 0; c < NCLS; ++c) {
      S2[c] += ea[c] * inva;                           // v_pk_fma_f32
      S2[c] += eb[c] * invb;
    }

    // Target-class gather (lines L1/L2-hot from the stream loads).
    const v2f xta = (v2f){xb[(size_t)t.x * HWPIX + pix + 0],
                          xb[(size_t)t.y * HWPIX + pix + 1]} * L2E;
    const v2f xtb = (v2f){xb[(size_t)t.z * HWPIX + pix + 2],
                          xb[(size_t)t.w * HWPIX + pix + 3]} * L2E;
    const v2f pta = (v2f){__builtin_amdgcn_exp2f(xta.x),
                          __builtin_amdgcn_exp2f(xta.y)} * inva;
    const v2f ptb = (v2f){__builtin_amdgcn_exp2f(xtb.x),
                          __builtin_amdgcn_exp2f(xtb.y)} * invb;
    atomicAdd(&sTPb[t.x][cp], pta.x);
    atomicAdd(&sTPb[t.y][cp], pta.y);
    atomicAdd(&sTPb[t.z][cp], ptb.x);
    atomicAdd(&sTPb[t.w][cp], ptb.y);
    atomicAdd(&sNb[t.x][cp], 1);
    atomicAdd(&sNb[t.y][cp], 1);
    atomicAdd(&sNb[t.z][cp], 1);
    atomicAdd(&sNb[t.w][cp], 1);

    // ---- retire the prefetch into cur (last iter: never read again) ----
#pragma unroll
    for (int c = 0; c < NCLS; ++c) cur[c] = nxt[c];
  }

  // Reduce S: fold pair, wave butterfly, wave leaders merge in LDS.
#pragma unroll
  for (int c = 0; c < NCLS; ++c) {
    float Sc = S2[c].x + S2[c].y;
    for (int off = 32; off; off >>= 1) Sc += __shfl_down(Sc, off);
    if ((tid & 63) == 0) atomicAdd(&sS[c], Sc);
  }
  __syncthreads();
  if (tid < NCLS) {
    float tp = 0.f;
    int n = 0;
#pragma unroll
    for (int i = 0; i < 32; ++i) { tp += sTPb[tid][i]; n += sNb[tid][i]; }
    float* p = part + (size_t)blockIdx.x * (3 * NCLS);
    p[tid] = sS[tid];
    p[NCLS + tid] = tp;
    p[2 * NCLS + tid] = (float)n;
  }

  // ---- last-block final reduction ----
  __syncthreads();  // part-slice stores drained (waitcnt before barrier)
  __shared__ int lastFlag;
  if (tid == 0) {
    __threadfence();  // release: make this block's slice device-visible
    lastFlag = (atomicAdd(counter, 1) == (NB * PB - 1));
  }
  __syncthreads();
  if (!lastFlag) return;
  __threadfence();  // acquire: invalidate stale cached partials

  float v = 0.f;
  if (tid < NB * NCLS) {
    const int bb = tid / NCLS;
    const int c = tid % NCLS;
    float S = 0.f, TP = 0.f, Nc = 0.f;
#pragma unroll 16
    for (int p = 0; p < PB; ++p) {
      const float* q = part + (size_t)(bb * PB + p) * (3 * NCLS);
      S += q[c];
      TP += q[NCLS + c];
      Nc += q[2 * NCLS + c];
    }
    const float FPv = S - TP;
    const float FNv = Nc - TP;
    const float tv = (TP + EPS_C) / (TP + ALPHA_C * FNv + BETA_C * FPv + EPS_C);
    v = 1.0f - tv;  // GAMMA == 1.0
  }
  for (int off = 32; off; off >>= 1) v += __shfl_down(v, off);
  __shared__ float wsum[4];
  if ((tid & 63) == 0) wsum[tid >> 6] = v;
  __syncthreads();
  if (tid == 0) out[0] = (wsum[0] + wsum[1] + wsum[2] + wsum[3]) / (float)NB;
}

extern "C" void kernel_launch(void* const* d_in, const int* in_sizes, int n_in,
                              void* d_out, int out_size, void* d_ws, size_t ws_size,
                              hipStream_t stream) {
  const float* x = (const float*)d_in[0];
  const int* tgt = (const int*)d_in[1];
  float* out = (float*)d_out;
  float* part = (float*)d_ws;
  int* counter = (int*)(part + NB * PB * 3 * NCLS);  // right after partials

  hipMemsetAsync(counter, 0, sizeof(int), stream);  // graph-capturable
  ftl_fused<<<NB * PB, 256, 0, stream>>>(x, tgt, part, counter, out);
}